// Round 11
// baseline (532.021 us; speedup 1.0000x reference)
//
#include <hip/hip_runtime.h>
#include <math.h>

#define HIDDEN 128
#define NCLS 40
#define BMAX 1024   // max buckets (256 nodes/bucket -> supports N <= 262144)

typedef __attribute__((ext_vector_type(8))) short short8;
typedef __attribute__((ext_vector_type(4))) float f32x4;
typedef __attribute__((ext_vector_type(2))) float f32x2;

__device__ __forceinline__ unsigned short f2bf(float f) {
    unsigned u = __float_as_uint(f);
    unsigned r = u + 0x7FFFu + ((u >> 16) & 1u);   // RNE
    return (unsigned short)(r >> 16);
}
__device__ __forceinline__ float bf_lo(unsigned u) { return __uint_as_float(u << 16); }
__device__ __forceinline__ float bf_hi(unsigned u) { return __uint_as_float(u & 0xFFFF0000u); }

// ---------------- weight prep (merged): WpreT + WT ----------------
__global__ void k_wprep(const float* __restrict__ Wp, const float* __restrict__ Wc,
                        const float* __restrict__ Wd, const float* __restrict__ Wa,
                        unsigned short* __restrict__ WpreT, unsigned short* __restrict__ WT) {
    int i = blockIdx.x * 256 + threadIdx.x;
    if (i < 16384) {
        int n = i >> 7, k = i & 127;
        WpreT[i] = f2bf(Wp[k * 128 + n]);
    } else if (i < 16384 + 4 * 18432) {
        int j = i - 16384;
        int d = j / 18432;
        int rem = j % 18432;
        int n = rem >> 7, k = rem & 127;
        float v = 0.f;
        if (n < 128)      v = Wc[d * 16384 + k * 128 + n];
        else if (n < 130) v = Wd[k * 2 + (n - 128)];
        else if (n < 133) v = Wa[k * 3 + (n - 130)];
        WT[j] = f2bf(v);
    }
}

// ---------------- CSR build (histogram-free: bucket counts -> bin -> scatter) ----------

__launch_bounds__(256)
__global__ void k_bcount(const int* __restrict__ ei, int E, int* __restrict__ bucket_cnt) {
    __shared__ int hist[BMAX];
    const int tid = threadIdx.x;
    for (int i = tid; i < BMAX; i += 256) hist[i] = 0;
    __syncthreads();
    const int e0 = blockIdx.x * 4096;
    #pragma unroll
    for (int i = 0; i < 16; i++) {
        int e = e0 + i * 256 + tid;
        if (e < E) atomicAdd(&hist[ei[E + e] >> 8], 1);
    }
    __syncthreads();
    for (int i = tid; i < BMAX; i += 256) {
        int v = hist[i];
        if (v > 0) atomicAdd(&bucket_cnt[i], v);
    }
}

// 256-thread exclusive scan over nb (<=1024) bins
__global__ void k_bscan(const int* __restrict__ bucket_cnt, int nb,
                        int* __restrict__ bucket_base, int* __restrict__ bucket_cursor) {
    __shared__ int sd[256];
    const int tid = threadIdx.x;
    int v[4];
    int sum = 0;
    #pragma unroll
    for (int j = 0; j < 4; j++) {
        int b = tid * 4 + j;
        v[j] = (b < nb) ? bucket_cnt[b] : 0;
        sum += v[j];
    }
    sd[tid] = sum;
    __syncthreads();
    #pragma unroll
    for (int off = 1; off < 256; off <<= 1) {
        int t = (tid >= off) ? sd[tid - off] : 0;
        __syncthreads();
        sd[tid] += t;
        __syncthreads();
    }
    int base = sd[tid] - sum;   // exclusive
    #pragma unroll
    for (int j = 0; j < 4; j++) {
        int b = tid * 4 + j;
        if (b < nb) {
            bucket_base[b] = base;
            bucket_cursor[b] = base;
            base += v[j];
        }
    }
}

// bin edges into bucket-grouped runs of packed (dstlocal<<24 | src). Needs N < 2^24.
__launch_bounds__(256)
__global__ void k_bin(const int* __restrict__ ei, int E,
                      int* __restrict__ bucket_cursor, unsigned* __restrict__ binned) {
    __shared__ int hist[BMAX];
    __shared__ int rankc[BMAX];
    __shared__ int lbase[BMAX];
    const int tid = threadIdx.x;
    const int e0 = blockIdx.x * 4096;
    for (int i = tid; i < BMAX; i += 256) { hist[i] = 0; rankc[i] = 0; }
    __syncthreads();
    int bkt[16];
    unsigned pk[16];
    #pragma unroll
    for (int i = 0; i < 16; i++) {
        int e = e0 + i * 256 + tid;
        if (e < E) {
            int s = ei[e];
            int d = ei[E + e];
            bkt[i] = d >> 8;
            pk[i] = ((unsigned)(d & 255) << 24) | (unsigned)s;
            atomicAdd(&hist[bkt[i]], 1);
        } else bkt[i] = -1;
    }
    __syncthreads();
    for (int i = tid; i < BMAX; i += 256)
        if (hist[i] > 0) lbase[i] = atomicAdd(&bucket_cursor[i], hist[i]);
    __syncthreads();
    #pragma unroll
    for (int i = 0; i < 16; i++) {
        if (bkt[i] >= 0) {
            int r = atomicAdd(&rankc[bkt[i]], 1);
            binned[lbase[bkt[i]] + r] = pk[i];
        }
    }
}

// one block per bucket: derive degrees, write row_start (N+1 entries) coalesced,
// scatter csr as fp8-row BYTE offsets (src*128).
__launch_bounds__(256)
__global__ void k_scatter(const unsigned* __restrict__ binned,
                          const int* __restrict__ bucket_base,
                          const int* __restrict__ bucket_cnt,
                          int* __restrict__ row_start,
                          int* __restrict__ csr_off, int N) {
    __shared__ int hist[256];
    __shared__ int rs[256];
    __shared__ int cur[256];
    const int tid = threadIdx.x;
    hist[tid] = 0;
    __syncthreads();
    const int base = bucket_base[blockIdx.x];
    const int cnt = bucket_cnt[blockIdx.x];
    for (int i = tid; i < cnt; i += 256)
        atomicAdd(&hist[binned[base + i] >> 24], 1);
    __syncthreads();
    int v = hist[tid];
    rs[tid] = v;
    __syncthreads();
    #pragma unroll
    for (int off = 1; off < 256; off <<= 1) {
        int t = (tid >= off) ? rs[tid - off] : 0;
        __syncthreads();
        rs[tid] += t;
        __syncthreads();
    }
    int gstart = base + rs[tid] - v;
    int n = (blockIdx.x << 8) + tid;
    if (n < N) {
        row_start[n] = gstart;
        if (n == N - 1) row_start[N] = gstart + v;   // sentinel: total edge count
    }
    __syncthreads();
    rs[tid] = gstart;
    cur[tid] = 0;
    __syncthreads();
    for (int i = tid; i < cnt; i += 256) {
        unsigned p = binned[base + i];
        int dl = (int)(p >> 24);
        int r = atomicAdd(&cur[dl], 1);
        csr_off[rs[dl] + r] = (int)((p & 0xFFFFFFu) << 7);   // src * 128 bytes (fp8 row)
    }
}

// ---------------- bf16 MFMA GEMM (512 threads + A-fragment hoist) ----------------
// 8 waves x 16 rows, 128-row tile, full-W LDS staging (rotated). ALL A-fragments
// for the wave's row are loaded BEFORE the staging loop: their HBM/L3 flight time
// hides under the ~37.5KB W staging + barrier, so the k0 loop is pure
// {ds_read -> MFMA} with no exposed global latency.

template <bool AF32, bool CTRL>
__launch_bounds__(512, 6)
__global__ void k_gemm_mfma(const void* __restrict__ Ain,
                            const unsigned short* __restrict__ Wt,
                            const float* __restrict__ bias,
                            unsigned short* __restrict__ Cb,
                            unsigned char* __restrict__ C8,
                            float* __restrict__ ctrl,
                            int M, int do_relu) {
    __shared__ unsigned short Ws[144 * 132];
    const int tid = threadIdx.x;
    const int lane = tid & 63;
    const int wv = tid >> 6;                      // 0..7
    const int row_blk = blockIdx.x * 128;
    const int l15 = lane & 15;
    const int q = lane >> 4;
    const int RWS = CTRL ? 144 : 128;
    const int TOT = RWS * 16;

    const int ar = row_blk + wv * 16 + l15;       // this wave's row
    const bool ok = ar < M;

    // ---- hoist: issue ALL A loads before staging (flight hides under staging) ----
    short8 af[4];
    float4 va[4][2];
    if (AF32) {
        const float* Af = (const float*)Ain;
        const float* qa = Af + (size_t)ar * HIDDEN + q * 8;
        const float4 zf = make_float4(0.f, 0.f, 0.f, 0.f);
        #pragma unroll
        for (int kk = 0; kk < 4; kk++) {
            va[kk][0] = ok ? *(const float4*)(qa + kk * 32) : zf;
            va[kk][1] = ok ? *(const float4*)(qa + kk * 32 + 4) : zf;
        }
    } else {
        const unsigned short* A = (const unsigned short*)Ain;
        const unsigned short* pa = A + (size_t)ar * HIDDEN + q * 8;
        const short8 z = {};
        #pragma unroll
        for (int kk = 0; kk < 4; kk++)
            af[kk] = ok ? *(const short8*)(pa + kk * 32) : z;
    }

    // phase-rotated staging: decorrelate address streams across blocks
    const int rot = (blockIdx.x * 512) % TOT;
    for (int ci = tid; ci < TOT; ci += 512) {
        int c = ci + rot;
        if (c >= TOT) c -= TOT;
        int r = c >> 4, ch = c & 15;
        *(uint4*)&Ws[r * 132 + ch * 8] = *(const uint4*)(Wt + (size_t)r * HIDDEN + ch * 8);
    }
    __syncthreads();

    if (AF32) {
        #pragma unroll
        for (int kk = 0; kk < 4; kk++) {
            float4 v0 = va[kk][0], v1 = va[kk][1];
            unsigned r0, r1, r2, r3;
            asm("v_cvt_pk_bf16_f32 %0, %1, %2" : "=v"(r0) : "v"(v0.x), "v"(v0.y));
            asm("v_cvt_pk_bf16_f32 %0, %1, %2" : "=v"(r1) : "v"(v0.z), "v"(v0.w));
            asm("v_cvt_pk_bf16_f32 %0, %1, %2" : "=v"(r2) : "v"(v1.x), "v"(v1.y));
            asm("v_cvt_pk_bf16_f32 %0, %1, %2" : "=v"(r3) : "v"(v1.z), "v"(v1.w));
            uint4 t;
            t.x = r0; t.y = r1; t.z = r2; t.w = r3;
            af[kk] = *(short8*)&t;
        }
    }

    f32x4 acc[8] = {};
    f32x4 acc5 = {};
    #pragma unroll
    for (int kk = 0; kk < 4; kk++) {
        const int k0 = kk * 32;
        #pragma unroll
        for (int ni = 0; ni < 8; ni++) {
            short8 bw = *(const short8*)&Ws[(ni * 16 + l15) * 132 + k0 + q * 8];
            acc[ni] = __builtin_amdgcn_mfma_f32_16x16x32_bf16(bw, af[kk], acc[ni], 0, 0, 0);
        }
        if (CTRL) {
            short8 bc = *(const short8*)&Ws[(128 + l15) * 132 + k0 + q * 8];
            acc5 = __builtin_amdgcn_mfma_f32_16x16x32_bf16(bc, af[kk], acc5, 0, 0, 0);
        }
    }
    if (ok) {
        const int node = ar;
        #pragma unroll
        for (int ni = 0; ni < 8; ni++) {
            int fb = ni * 16 + q * 4;
            float4 bv = *(const float4*)&bias[fb];
            float o0 = acc[ni][0] + bv.x;
            float o1 = acc[ni][1] + bv.y;
            float o2 = acc[ni][2] + bv.z;
            float o3 = acc[ni][3] + bv.w;
            if (do_relu) {
                o0 = fmaxf(o0, 0.f); o1 = fmaxf(o1, 0.f);
                o2 = fmaxf(o2, 0.f); o3 = fmaxf(o3, 0.f);
            }
            // packed bf16 convert (RNE, bit-identical to f2bf)
            unsigned plo, phi;
            asm("v_cvt_pk_bf16_f32 %0, %1, %2" : "=v"(plo) : "v"(o0), "v"(o1));
            asm("v_cvt_pk_bf16_f32 %0, %1, %2" : "=v"(phi) : "v"(o2), "v"(o3));
            uint2 ov;
            ov.x = plo; ov.y = phi;
            *(uint2*)(Cb + (size_t)node * HIDDEN + fb) = ov;
            if (CTRL) {
                unsigned w8 = 0;
                w8 = __builtin_amdgcn_cvt_pk_fp8_f32(o0, o1, w8, 0);
                w8 = __builtin_amdgcn_cvt_pk_fp8_f32(o2, o3, w8, 1);
                *(unsigned*)(C8 + (size_t)node * HIDDEN + fb) = w8;
            }
        }
        if (CTRL) {
            if (q == 0) {
                *(float4*)(ctrl + (size_t)node * 8) =
                    make_float4(acc5[0], acc5[1], acc5[2], acc5[3]);
            } else if (q == 1) {
                ctrl[(size_t)node * 8 + 4] = acc5[0];
            }
        }
    }
}

// ---------------- fused depth step (R4 version — best measured) ----------------
// one wave per node; lane owns 2 features end-to-end (64 lanes x 2B = one 128B fp8
// row per edge). Two-phase gather: batch-issue 16 independent loads into named
// registers (readlane->SALU base), THEN convert+accumulate. ~16 loads in flight.

// phase 1: issue load for edge (JJ)+K into uK
#define LDE(K, JJ)                                                            \
    unsigned u##K = *(const unsigned short*)(                                 \
        ht8 + (unsigned)__builtin_amdgcn_readlane(soff, (JJ) + K) + lane2);
// phase 2: consume uK
#define ACE(K)                                                                \
    { f32x2 p_ = __builtin_amdgcn_cvt_pk_f32_fp8(u##K, 0);                    \
      sacc += p_;                                                             \
      mx0 = fmaxf(mx0, p_.x); mx1 = fmaxf(mx1, p_.y); }

__launch_bounds__(256)
__global__ void k_depth(const unsigned char* __restrict__ ht8,
                        const unsigned short* __restrict__ ht,
                        unsigned short* __restrict__ h_out,
                        float* __restrict__ cp, float* __restrict__ wsel,
                        const float* __restrict__ ctrl,
                        const int* __restrict__ row_start,   // N+1 entries
                        const int* __restrict__ csr_off,
                        const float* __restrict__ bd, const float* __restrict__ ba,
                        int N, int first) {
    const int lane = threadIdx.x & 63;
    const int wave = threadIdx.x >> 6;
    const int node = blockIdx.x * 4 + wave;
    if (node >= N) return;
    const int nodeu = __builtin_amdgcn_readfirstlane(node);
    const int lane2 = lane << 1;     // byte offset into fp8 row (2 features/lane)

    // chase level 1: row extent (uniform s_loads, one level)
    const int start = row_start[nodeu];
    const int cnt = row_start[nodeu + 1] - start;

    // chase level 2 + independent loads: issue before softmax VALU
    int soff = (lane < cnt) ? csr_off[start + lane] : 0;
    unsigned su = *(const unsigned*)((const char*)ht + ((size_t)nodeu << 8) + (lane << 2));
    float4 c4 = *(const float4*)(ctrl + (size_t)nodeu * 8);
    float cl4 = ctrl[(size_t)nodeu * 8 + 4];

    // controller softmaxes (overlap csr_off/self-row flight)
    float d0 = c4.x + bd[0], d1 = c4.y + bd[1];
    float a0 = c4.z + ba[0], a1 = c4.w + ba[1], a2 = cl4 + ba[2];
    float m2 = fmaxf(d0, d1);
    float e0 = __expf(d0 - m2), e1 = __expf(d1 - m2);
    float inv2 = __builtin_amdgcn_rcpf(e0 + e1);
    float sp0 = e0 * inv2, sp1 = e1 * inv2;
    float m3 = fmaxf(fmaxf(a0, a1), a2);
    float f0 = __expf(a0 - m3), f1 = __expf(a1 - m3), f2 = __expf(a2 - m3);
    float inv3 = __builtin_amdgcn_rcpf(f0 + f1 + f2);
    float ap0 = f0 * inv3, ap1 = f1 * inv3, ap2 = f2 * inv3;

    f32x2 sacc = {0.f, 0.f};
    float mx0 = -3.4e38f, mx1 = -3.4e38f;

    for (int eb = 0; eb < cnt; eb += 64) {
        if (eb) {
            int i2 = eb + lane;
            soff = (i2 < cnt) ? csr_off[start + i2] : 0;
        }
        int lim = min(64, cnt - eb);
        int j = 0;
        for (; j + 16 <= lim; j += 16) {
            LDE(0, j)  LDE(1, j)  LDE(2, j)  LDE(3, j)
            LDE(4, j)  LDE(5, j)  LDE(6, j)  LDE(7, j)
            LDE(8, j)  LDE(9, j)  LDE(10, j) LDE(11, j)
            LDE(12, j) LDE(13, j) LDE(14, j) LDE(15, j)
            ACE(0)  ACE(1)  ACE(2)  ACE(3)
            ACE(4)  ACE(5)  ACE(6)  ACE(7)
            ACE(8)  ACE(9)  ACE(10) ACE(11)
            ACE(12) ACE(13) ACE(14) ACE(15)
        }
        if (j + 8 <= lim) {
            LDE(0, j) LDE(1, j) LDE(2, j) LDE(3, j)
            LDE(4, j) LDE(5, j) LDE(6, j) LDE(7, j)
            ACE(0) ACE(1) ACE(2) ACE(3)
            ACE(4) ACE(5) ACE(6) ACE(7)
            j += 8;
        }
        if (j + 4 <= lim) {
            LDE(0, j) LDE(1, j) LDE(2, j) LDE(3, j)
            ACE(0) ACE(1) ACE(2) ACE(3)
            j += 4;
        }
        for (; j < lim; j++) {
            LDE(0, j)
            ACE(0)
        }
    }

    if (cnt == 0) { mx0 = 0.f; mx1 = 0.f; }    // isolated nodes -> max = 0
    float invd = __builtin_amdgcn_rcpf(fmaxf((float)cnt, 1.0f));
    float h0 = ap0 * (sacc.x * invd) + ap1 * mx0 + ap2 * bf_lo(su);
    float h1 = ap0 * (sacc.y * invd) + ap1 * mx1 + ap2 * bf_hi(su);
    h0 = fmaxf(h0, 0.f);
    h1 = fmaxf(h1, 0.f);
    unsigned po = ((unsigned)f2bf(h1) << 16) | (unsigned)f2bf(h0);
    *(unsigned*)((char*)h_out + ((size_t)nodeu << 8) + (lane << 2)) = po;

    if (lane == 0) {
        float cpv = first ? 1.0f : cp[nodeu];
        wsel[nodeu] = cpv * sp1;
        cp[nodeu] = cpv * sp0;
    }
}

// ---------------- post: sel = sum_d w_d * h_{d+1}; logits; log_softmax ----------------

__launch_bounds__(256)
__global__ void k_post(const unsigned short* __restrict__ h_all, size_t hstride,
                       const float* __restrict__ wsel, int N,
                       const float* __restrict__ Wp, const float* __restrict__ bp,
                       float* __restrict__ out) {
    __shared__ float Ss[32][132];
    __shared__ float Wt[NCLS][132];
    __shared__ float bs[NCLS];
    const int tid = threadIdx.x;
    const int n0 = blockIdx.x * 32;

    for (int i = tid; i < (HIDDEN * NCLS) / 4; i += 256) {
        float4 v = *(const float4*)&Wp[i * 4];
        int f = i * 4;
        int k = f / NCLS, c = f % NCLS;
        float e[4] = {v.x, v.y, v.z, v.w};
        #pragma unroll
        for (int j = 0; j < 4; j++) {
            int cc = c + j, kk = k;
            if (cc >= NCLS) { cc -= NCLS; kk++; }
            Wt[cc][kk] = e[j];
        }
    }
    if (tid < NCLS) bs[tid] = bp[tid];

    const int node_l = tid >> 3;
    const int kc = (tid & 7) * 16;
    const int ng = n0 + node_l;
    float sel[16];
    #pragma unroll
    for (int i = 0; i < 16; i++) sel[i] = 0.f;
    if (ng < N) {
        #pragma unroll
        for (int d = 0; d < 4; d++) {
            float w = wsel[(size_t)d * N + ng];
            const unsigned short* hrow = h_all + (size_t)(d + 1) * hstride + (size_t)ng * HIDDEN;
            #pragma unroll
            for (int u = 0; u < 2; u++) {
                uint4 p = *(const uint4*)(hrow + kc + u * 8);
                unsigned vs[4] = {p.x, p.y, p.z, p.w};
                #pragma unroll
                for (int j = 0; j < 4; j++) {
                    sel[u * 8 + j * 2 + 0] += w * bf_lo(vs[j]);
                    sel[u * 8 + j * 2 + 1] += w * bf_hi(vs[j]);
                }
            }
        }
    }
    #pragma unroll
    for (int u = 0; u < 4; u++)
        *(float4*)&Ss[node_l][kc + u * 4] =
            make_float4(sel[u * 4], sel[u * 4 + 1], sel[u * 4 + 2], sel[u * 4 + 3]);
    __syncthreads();

    const int c0 = (tid & 7) * 5;
    float z[5];
    #pragma unroll
    for (int i = 0; i < 5; i++) z[i] = bs[c0 + i];
    for (int k = 0; k < HIDDEN; k += 4) {
        float4 s4 = *(const float4*)&Ss[node_l][k];
        #pragma unroll
        for (int i = 0; i < 5; i++) {
            float4 w4 = *(const float4*)&Wt[c0 + i][k];
            z[i] += s4.x * w4.x + s4.y * w4.y + s4.z * w4.z + s4.w * w4.w;
        }
    }
    float m = z[0];
    #pragma unroll
    for (int i = 1; i < 5; i++) m = fmaxf(m, z[i]);
    #pragma unroll
    for (int off = 1; off < 8; off <<= 1) m = fmaxf(m, __shfl_xor(m, off));
    float s = 0.f;
    #pragma unroll
    for (int i = 0; i < 5; i++) s += expf(z[i] - m);
    #pragma unroll
    for (int off = 1; off < 8; off <<= 1) s += __shfl_xor(s, off);
    float lg = m + logf(s);
    if (ng < N) {
        #pragma unroll
        for (int i = 0; i < 5; i++)
            out[(size_t)ng * NCLS + c0 + i] = z[i] - lg;
    }
}

// ---------------- launch ----------------

extern "C" void kernel_launch(void* const* d_in, const int* in_sizes, int n_in,
                              void* d_out, int out_size, void* d_ws, size_t ws_size,
                              hipStream_t stream) {
    const float* x      = (const float*)d_in[0];
    const int*   ei     = (const int*)d_in[1];
    const float* W_pre  = (const float*)d_in[2];
    const float* b_pre  = (const float*)d_in[3];
    const float* W_dep  = (const float*)d_in[4];
    const float* b_dep  = (const float*)d_in[5];
    const float* W_aggr = (const float*)d_in[6];
    const float* b_aggr = (const float*)d_in[7];
    const float* W_conv = (const float*)d_in[8];
    const float* b_conv = (const float*)d_in[9];
    const float* W_post = (const float*)d_in[10];
    const float* b_post = (const float*)d_in[11];

    const int N = in_sizes[0] / HIDDEN;
    const int E = in_sizes[1] / 2;
    const int nbuckets = (N + 255) >> 8;

    char* ws = (char*)d_ws;
    size_t off = 0;
    auto alloc = [&](size_t bytes) -> void* {
        void* p = ws + off;
        off += (bytes + 255) & ~(size_t)255;
        return p;
    };
    const size_t hstride = (size_t)N * HIDDEN;
    unsigned short* h_all  = (unsigned short*)alloc(5 * hstride * 2);  // h_0..h_4
    unsigned short* ht     = (unsigned short*)alloc(hstride * 2);
    unsigned char*  ht8    = (unsigned char*)alloc(hstride);           // fp8 gather copy
    float* cp       = (float*)alloc((size_t)N * 4);
    float* wsel     = (float*)alloc((size_t)4 * N * 4);
    float* ctrl     = (float*)alloc((size_t)N * 8 * 4);
    unsigned short* WpreT = (unsigned short*)alloc(128 * 128 * 2);
    unsigned short* WT    = (unsigned short*)alloc(4 * 144 * 128 * 2);
    int*   row_start= (int*)alloc((size_t)(N + 8) * 4);   // N+1 used (sentinel at [N])
    int*   bucket_cnt    = (int*)alloc(BMAX * 4);
    int*   bucket_base   = (int*)alloc(BMAX * 4);
    int*   bucket_cursor = (int*)alloc(BMAX * 4);
    int*   csr_off  = (int*)alloc((size_t)E * 4);
    unsigned* binned = (unsigned*)alloc((size_t)E * 4);

    hipMemsetAsync(bucket_cnt, 0, BMAX * 4, stream);

    int ebb = (E + 4095) / 4096;
    k_bcount<<<ebb, 256, 0, stream>>>(ei, E, bucket_cnt);
    k_bscan<<<1, 256, 0, stream>>>(bucket_cnt, nbuckets, bucket_base, bucket_cursor);
    k_bin<<<ebb, 256, 0, stream>>>(ei, E, bucket_cursor, binned);
    k_scatter<<<nbuckets, 256, 0, stream>>>(binned, bucket_base, bucket_cnt,
                                            row_start, csr_off, N);

    int wtot = 16384 + 4 * 18432;
    k_wprep<<<(wtot + 255) / 256, 256, 0, stream>>>(W_pre, W_conv, W_dep, W_aggr,
                                                    WpreT, WT);

    int gblk = (N + 127) / 128;
    k_gemm_mfma<true, false><<<gblk, 512, 0, stream>>>(x, WpreT, b_pre, h_all,
                                                       nullptr, nullptr, N, 1);

    int nb4 = (N + 3) / 4;
    for (int d = 0; d < 4; d++) {
        unsigned short* h_d  = h_all + (size_t)d * hstride;
        unsigned short* h_n  = h_all + (size_t)(d + 1) * hstride;
        k_gemm_mfma<false, true><<<gblk, 512, 0, stream>>>(h_d, WT + (size_t)d * 18432,
                                                           b_conv + (size_t)d * HIDDEN,
                                                           ht, ht8, ctrl, N, 0);
        k_depth<<<nb4, 256, 0, stream>>>(ht8, ht, h_n, cp, wsel + (size_t)d * N, ctrl,
                                         row_start, csr_off,
                                         b_dep, b_aggr, N, d == 0 ? 1 : 0);
    }
    k_post<<<(N + 31) / 32, 256, 0, stream>>>(h_all, hstride, wsel, N,
                                              W_post, b_post, (float*)d_out);
}

// Round 12
// 515.683 us; speedup vs baseline: 1.0317x; 1.0317x over previous
//
#include <hip/hip_runtime.h>
#include <math.h>

#define HIDDEN 128
#define NCLS 40
#define BMAX 1024   // max buckets (256 nodes/bucket -> supports N <= 262144)

typedef __attribute__((ext_vector_type(8))) short short8;
typedef __attribute__((ext_vector_type(4))) float f32x4;
typedef __attribute__((ext_vector_type(2))) float f32x2;

__device__ __forceinline__ unsigned short f2bf(float f) {
    unsigned u = __float_as_uint(f);
    unsigned r = u + 0x7FFFu + ((u >> 16) & 1u);   // RNE
    return (unsigned short)(r >> 16);
}
__device__ __forceinline__ float bf_lo(unsigned u) { return __uint_as_float(u << 16); }
__device__ __forceinline__ float bf_hi(unsigned u) { return __uint_as_float(u & 0xFFFF0000u); }

// ---------------- weight prep (merged): WpreT + WT ----------------
__global__ void k_wprep(const float* __restrict__ Wp, const float* __restrict__ Wc,
                        const float* __restrict__ Wd, const float* __restrict__ Wa,
                        unsigned short* __restrict__ WpreT, unsigned short* __restrict__ WT) {
    int i = blockIdx.x * 256 + threadIdx.x;
    if (i < 16384) {
        int n = i >> 7, k = i & 127;
        WpreT[i] = f2bf(Wp[k * 128 + n]);
    } else if (i < 16384 + 4 * 18432) {
        int j = i - 16384;
        int d = j / 18432;
        int rem = j % 18432;
        int n = rem >> 7, k = rem & 127;
        float v = 0.f;
        if (n < 128)      v = Wc[d * 16384 + k * 128 + n];
        else if (n < 130) v = Wd[k * 2 + (n - 128)];
        else if (n < 133) v = Wa[k * 3 + (n - 130)];
        WT[j] = f2bf(v);
    }
}

// ---------------- CSR build (histogram-free: bucket counts -> bin -> scatter) ----------

__launch_bounds__(256)
__global__ void k_bcount(const int* __restrict__ ei, int E, int* __restrict__ bucket_cnt) {
    __shared__ int hist[BMAX];
    const int tid = threadIdx.x;
    for (int i = tid; i < BMAX; i += 256) hist[i] = 0;
    __syncthreads();
    const int e0 = blockIdx.x * 4096;
    #pragma unroll
    for (int i = 0; i < 16; i++) {
        int e = e0 + i * 256 + tid;
        if (e < E) atomicAdd(&hist[ei[E + e] >> 8], 1);
    }
    __syncthreads();
    for (int i = tid; i < BMAX; i += 256) {
        int v = hist[i];
        if (v > 0) atomicAdd(&bucket_cnt[i], v);
    }
}

// 256-thread exclusive scan over nb (<=1024) bins
__global__ void k_bscan(const int* __restrict__ bucket_cnt, int nb,
                        int* __restrict__ bucket_base, int* __restrict__ bucket_cursor) {
    __shared__ int sd[256];
    const int tid = threadIdx.x;
    int v[4];
    int sum = 0;
    #pragma unroll
    for (int j = 0; j < 4; j++) {
        int b = tid * 4 + j;
        v[j] = (b < nb) ? bucket_cnt[b] : 0;
        sum += v[j];
    }
    sd[tid] = sum;
    __syncthreads();
    #pragma unroll
    for (int off = 1; off < 256; off <<= 1) {
        int t = (tid >= off) ? sd[tid - off] : 0;
        __syncthreads();
        sd[tid] += t;
        __syncthreads();
    }
    int base = sd[tid] - sum;   // exclusive
    #pragma unroll
    for (int j = 0; j < 4; j++) {
        int b = tid * 4 + j;
        if (b < nb) {
            bucket_base[b] = base;
            bucket_cursor[b] = base;
            base += v[j];
        }
    }
}

// bin edges into bucket-grouped runs of packed (dstlocal<<24 | src). Needs N < 2^24.
__launch_bounds__(256)
__global__ void k_bin(const int* __restrict__ ei, int E,
                      int* __restrict__ bucket_cursor, unsigned* __restrict__ binned) {
    __shared__ int hist[BMAX];
    __shared__ int rankc[BMAX];
    __shared__ int lbase[BMAX];
    const int tid = threadIdx.x;
    const int e0 = blockIdx.x * 4096;
    for (int i = tid; i < BMAX; i += 256) { hist[i] = 0; rankc[i] = 0; }
    __syncthreads();
    int bkt[16];
    unsigned pk[16];
    #pragma unroll
    for (int i = 0; i < 16; i++) {
        int e = e0 + i * 256 + tid;
        if (e < E) {
            int s = ei[e];
            int d = ei[E + e];
            bkt[i] = d >> 8;
            pk[i] = ((unsigned)(d & 255) << 24) | (unsigned)s;
            atomicAdd(&hist[bkt[i]], 1);
        } else bkt[i] = -1;
    }
    __syncthreads();
    for (int i = tid; i < BMAX; i += 256)
        if (hist[i] > 0) lbase[i] = atomicAdd(&bucket_cursor[i], hist[i]);
    __syncthreads();
    #pragma unroll
    for (int i = 0; i < 16; i++) {
        if (bkt[i] >= 0) {
            int r = atomicAdd(&rankc[bkt[i]], 1);
            binned[lbase[bkt[i]] + r] = pk[i];
        }
    }
}

// one block per bucket: derive degrees, write row_start (N+1 entries) coalesced,
// scatter csr as fp8-row BYTE offsets (src*128).
__launch_bounds__(256)
__global__ void k_scatter(const unsigned* __restrict__ binned,
                          const int* __restrict__ bucket_base,
                          const int* __restrict__ bucket_cnt,
                          int* __restrict__ row_start,
                          int* __restrict__ csr_off, int N) {
    __shared__ int hist[256];
    __shared__ int rs[256];
    __shared__ int cur[256];
    const int tid = threadIdx.x;
    hist[tid] = 0;
    __syncthreads();
    const int base = bucket_base[blockIdx.x];
    const int cnt = bucket_cnt[blockIdx.x];
    for (int i = tid; i < cnt; i += 256)
        atomicAdd(&hist[binned[base + i] >> 24], 1);
    __syncthreads();
    int v = hist[tid];
    rs[tid] = v;
    __syncthreads();
    #pragma unroll
    for (int off = 1; off < 256; off <<= 1) {
        int t = (tid >= off) ? rs[tid - off] : 0;
        __syncthreads();
        rs[tid] += t;
        __syncthreads();
    }
    int gstart = base + rs[tid] - v;
    int n = (blockIdx.x << 8) + tid;
    if (n < N) {
        row_start[n] = gstart;
        if (n == N - 1) row_start[N] = gstart + v;   // sentinel: total edge count
    }
    __syncthreads();
    rs[tid] = gstart;
    cur[tid] = 0;
    __syncthreads();
    for (int i = tid; i < cnt; i += 256) {
        unsigned p = binned[base + i];
        int dl = (int)(p >> 24);
        int r = atomicAdd(&cur[dl], 1);
        csr_off[rs[dl] + r] = (int)((p & 0xFFFFFFu) << 7);   // src * 128 bytes (fp8 row)
    }
}

// ---------------- bf16 MFMA GEMM (512-thread blocks: 2x waves, half-size waves) --
// R10 version (best measured). 8 waves x 16 rows, 128-row tile, full-W LDS
// staging (rotated). A-loads in-loop (the R11 source-level hoist regressed:
// compiler sank the loads and produced a worse schedule).

template <bool AF32, bool CTRL>
__launch_bounds__(512, 6)
__global__ void k_gemm_mfma(const void* __restrict__ Ain,
                            const unsigned short* __restrict__ Wt,
                            const float* __restrict__ bias,
                            unsigned short* __restrict__ Cb,
                            unsigned char* __restrict__ C8,
                            float* __restrict__ ctrl,
                            int M, int do_relu) {
    __shared__ unsigned short Ws[144 * 132];
    const int tid = threadIdx.x;
    const int lane = tid & 63;
    const int wv = tid >> 6;                      // 0..7
    const int row_blk = blockIdx.x * 128;
    const int l15 = lane & 15;
    const int q = lane >> 4;
    const int RWS = CTRL ? 144 : 128;
    const int TOT = RWS * 16;

    // phase-rotated staging: decorrelate address streams across blocks
    const int rot = (blockIdx.x * 512) % TOT;
    for (int ci = tid; ci < TOT; ci += 512) {
        int c = ci + rot;
        if (c >= TOT) c -= TOT;
        int r = c >> 4, ch = c & 15;
        *(uint4*)&Ws[r * 132 + ch * 8] = *(const uint4*)(Wt + (size_t)r * HIDDEN + ch * 8);
    }
    __syncthreads();

    const int ar = row_blk + wv * 16 + l15;       // this wave's row
    const bool ok = ar < M;

    f32x4 acc[8] = {};
    f32x4 acc5 = {};
    for (int k0 = 0; k0 < 128; k0 += 32) {
        short8 af;
        if (AF32) {
            const float* A = (const float*)Ain;
            float4 v0 = make_float4(0.f, 0.f, 0.f, 0.f);
            float4 v1 = make_float4(0.f, 0.f, 0.f, 0.f);
            if (ok) {
                v0 = *(const float4*)(A + (size_t)ar * HIDDEN + k0 + q * 8);
                v1 = *(const float4*)(A + (size_t)ar * HIDDEN + k0 + q * 8 + 4);
            }
            unsigned r0, r1, r2, r3;
            asm("v_cvt_pk_bf16_f32 %0, %1, %2" : "=v"(r0) : "v"(v0.x), "v"(v0.y));
            asm("v_cvt_pk_bf16_f32 %0, %1, %2" : "=v"(r1) : "v"(v0.z), "v"(v0.w));
            asm("v_cvt_pk_bf16_f32 %0, %1, %2" : "=v"(r2) : "v"(v1.x), "v"(v1.y));
            asm("v_cvt_pk_bf16_f32 %0, %1, %2" : "=v"(r3) : "v"(v1.z), "v"(v1.w));
            uint4 t;
            t.x = r0; t.y = r1; t.z = r2; t.w = r3;
            af = *(short8*)&t;
        } else {
            const unsigned short* A = (const unsigned short*)Ain;
            short8 t = {};
            if (ok) t = *(const short8*)(A + (size_t)ar * HIDDEN + k0 + q * 8);
            af = t;
        }
        #pragma unroll
        for (int ni = 0; ni < 8; ni++) {
            short8 bw = *(const short8*)&Ws[(ni * 16 + l15) * 132 + k0 + q * 8];
            acc[ni] = __builtin_amdgcn_mfma_f32_16x16x32_bf16(bw, af, acc[ni], 0, 0, 0);
        }
        if (CTRL) {
            short8 bc = *(const short8*)&Ws[(128 + l15) * 132 + k0 + q * 8];
            acc5 = __builtin_amdgcn_mfma_f32_16x16x32_bf16(bc, af, acc5, 0, 0, 0);
        }
    }
    if (ok) {
        const int node = ar;
        #pragma unroll
        for (int ni = 0; ni < 8; ni++) {
            int fb = ni * 16 + q * 4;
            float4 bv = *(const float4*)&bias[fb];
            float o0 = acc[ni][0] + bv.x;
            float o1 = acc[ni][1] + bv.y;
            float o2 = acc[ni][2] + bv.z;
            float o3 = acc[ni][3] + bv.w;
            if (do_relu) {
                o0 = fmaxf(o0, 0.f); o1 = fmaxf(o1, 0.f);
                o2 = fmaxf(o2, 0.f); o3 = fmaxf(o3, 0.f);
            }
            // packed bf16 convert (RNE, bit-identical to f2bf)
            unsigned plo, phi;
            asm("v_cvt_pk_bf16_f32 %0, %1, %2" : "=v"(plo) : "v"(o0), "v"(o1));
            asm("v_cvt_pk_bf16_f32 %0, %1, %2" : "=v"(phi) : "v"(o2), "v"(o3));
            uint2 ov;
            ov.x = plo; ov.y = phi;
            *(uint2*)(Cb + (size_t)node * HIDDEN + fb) = ov;
            if (CTRL) {
                unsigned w8 = 0;
                w8 = __builtin_amdgcn_cvt_pk_fp8_f32(o0, o1, w8, 0);
                w8 = __builtin_amdgcn_cvt_pk_fp8_f32(o2, o3, w8, 1);
                *(unsigned*)(C8 + (size_t)node * HIDDEN + fb) = w8;
            }
        }
        if (CTRL) {
            if (q == 0) {
                *(float4*)(ctrl + (size_t)node * 8) =
                    make_float4(acc5[0], acc5[1], acc5[2], acc5[3]);
            } else if (q == 1) {
                ctrl[(size_t)node * 8 + 4] = acc5[0];
            }
        }
    }
}

// ---------------- fused depth step (R4 version — best measured) ----------------
// one wave per node; lane owns 2 features end-to-end (64 lanes x 2B = one 128B fp8
// row per edge). Two-phase gather: batch-issue 16 independent loads into named
// registers (readlane->SALU base), THEN convert+accumulate. ~16 loads in flight.

// phase 1: issue load for edge (JJ)+K into uK
#define LDE(K, JJ)                                                            \
    unsigned u##K = *(const unsigned short*)(                                 \
        ht8 + (unsigned)__builtin_amdgcn_readlane(soff, (JJ) + K) + lane2);
// phase 2: consume uK
#define ACE(K)                                                                \
    { f32x2 p_ = __builtin_amdgcn_cvt_pk_f32_fp8(u##K, 0);                    \
      sacc += p_;                                                             \
      mx0 = fmaxf(mx0, p_.x); mx1 = fmaxf(mx1, p_.y); }

__launch_bounds__(256)
__global__ void k_depth(const unsigned char* __restrict__ ht8,
                        const unsigned short* __restrict__ ht,
                        unsigned short* __restrict__ h_out,
                        float* __restrict__ cp, float* __restrict__ wsel,
                        const float* __restrict__ ctrl,
                        const int* __restrict__ row_start,   // N+1 entries
                        const int* __restrict__ csr_off,
                        const float* __restrict__ bd, const float* __restrict__ ba,
                        int N, int first) {
    const int lane = threadIdx.x & 63;
    const int wave = threadIdx.x >> 6;
    const int node = blockIdx.x * 4 + wave;
    if (node >= N) return;
    const int nodeu = __builtin_amdgcn_readfirstlane(node);
    const int lane2 = lane << 1;     // byte offset into fp8 row (2 features/lane)

    // chase level 1: row extent (uniform s_loads, one level)
    const int start = row_start[nodeu];
    const int cnt = row_start[nodeu + 1] - start;

    // chase level 2 + independent loads: issue before softmax VALU
    int soff = (lane < cnt) ? csr_off[start + lane] : 0;
    unsigned su = *(const unsigned*)((const char*)ht + ((size_t)nodeu << 8) + (lane << 2));
    float4 c4 = *(const float4*)(ctrl + (size_t)nodeu * 8);
    float cl4 = ctrl[(size_t)nodeu * 8 + 4];

    // controller softmaxes (overlap csr_off/self-row flight)
    float d0 = c4.x + bd[0], d1 = c4.y + bd[1];
    float a0 = c4.z + ba[0], a1 = c4.w + ba[1], a2 = cl4 + ba[2];
    float m2 = fmaxf(d0, d1);
    float e0 = __expf(d0 - m2), e1 = __expf(d1 - m2);
    float inv2 = __builtin_amdgcn_rcpf(e0 + e1);
    float sp0 = e0 * inv2, sp1 = e1 * inv2;
    float m3 = fmaxf(fmaxf(a0, a1), a2);
    float f0 = __expf(a0 - m3), f1 = __expf(a1 - m3), f2 = __expf(a2 - m3);
    float inv3 = __builtin_amdgcn_rcpf(f0 + f1 + f2);
    float ap0 = f0 * inv3, ap1 = f1 * inv3, ap2 = f2 * inv3;

    f32x2 sacc = {0.f, 0.f};
    float mx0 = -3.4e38f, mx1 = -3.4e38f;

    for (int eb = 0; eb < cnt; eb += 64) {
        if (eb) {
            int i2 = eb + lane;
            soff = (i2 < cnt) ? csr_off[start + i2] : 0;
        }
        int lim = min(64, cnt - eb);
        int j = 0;
        for (; j + 16 <= lim; j += 16) {
            LDE(0, j)  LDE(1, j)  LDE(2, j)  LDE(3, j)
            LDE(4, j)  LDE(5, j)  LDE(6, j)  LDE(7, j)
            LDE(8, j)  LDE(9, j)  LDE(10, j) LDE(11, j)
            LDE(12, j) LDE(13, j) LDE(14, j) LDE(15, j)
            ACE(0)  ACE(1)  ACE(2)  ACE(3)
            ACE(4)  ACE(5)  ACE(6)  ACE(7)
            ACE(8)  ACE(9)  ACE(10) ACE(11)
            ACE(12) ACE(13) ACE(14) ACE(15)
        }
        if (j + 8 <= lim) {
            LDE(0, j) LDE(1, j) LDE(2, j) LDE(3, j)
            LDE(4, j) LDE(5, j) LDE(6, j) LDE(7, j)
            ACE(0) ACE(1) ACE(2) ACE(3)
            ACE(4) ACE(5) ACE(6) ACE(7)
            j += 8;
        }
        if (j + 4 <= lim) {
            LDE(0, j) LDE(1, j) LDE(2, j) LDE(3, j)
            ACE(0) ACE(1) ACE(2) ACE(3)
            j += 4;
        }
        for (; j < lim; j++) {
            LDE(0, j)
            ACE(0)
        }
    }

    if (cnt == 0) { mx0 = 0.f; mx1 = 0.f; }    // isolated nodes -> max = 0
    float invd = __builtin_amdgcn_rcpf(fmaxf((float)cnt, 1.0f));
    float h0 = ap0 * (sacc.x * invd) + ap1 * mx0 + ap2 * bf_lo(su);
    float h1 = ap0 * (sacc.y * invd) + ap1 * mx1 + ap2 * bf_hi(su);
    h0 = fmaxf(h0, 0.f);
    h1 = fmaxf(h1, 0.f);
    unsigned po = ((unsigned)f2bf(h1) << 16) | (unsigned)f2bf(h0);
    *(unsigned*)((char*)h_out + ((size_t)nodeu << 8) + (lane << 2)) = po;

    if (lane == 0) {
        float cpv = first ? 1.0f : cp[nodeu];
        wsel[nodeu] = cpv * sp1;
        cp[nodeu] = cpv * sp0;
    }
}

// ---------------- post: sel = sum_d w_d * h_{d+1}; logits; log_softmax ----------------

__launch_bounds__(256)
__global__ void k_post(const unsigned short* __restrict__ h_all, size_t hstride,
                       const float* __restrict__ wsel, int N,
                       const float* __restrict__ Wp, const float* __restrict__ bp,
                       float* __restrict__ out) {
    __shared__ float Ss[32][132];
    __shared__ float Wt[NCLS][132];
    __shared__ float bs[NCLS];
    const int tid = threadIdx.x;
    const int n0 = blockIdx.x * 32;

    for (int i = tid; i < (HIDDEN * NCLS) / 4; i += 256) {
        float4 v = *(const float4*)&Wp[i * 4];
        int f = i * 4;
        int k = f / NCLS, c = f % NCLS;
        float e[4] = {v.x, v.y, v.z, v.w};
        #pragma unroll
        for (int j = 0; j < 4; j++) {
            int cc = c + j, kk = k;
            if (cc >= NCLS) { cc -= NCLS; kk++; }
            Wt[cc][kk] = e[j];
        }
    }
    if (tid < NCLS) bs[tid] = bp[tid];

    const int node_l = tid >> 3;
    const int kc = (tid & 7) * 16;
    const int ng = n0 + node_l;
    float sel[16];
    #pragma unroll
    for (int i = 0; i < 16; i++) sel[i] = 0.f;
    if (ng < N) {
        #pragma unroll
        for (int d = 0; d < 4; d++) {
            float w = wsel[(size_t)d * N + ng];
            const unsigned short* hrow = h_all + (size_t)(d + 1) * hstride + (size_t)ng * HIDDEN;
            #pragma unroll
            for (int u = 0; u < 2; u++) {
                uint4 p = *(const uint4*)(hrow + kc + u * 8);
                unsigned vs[4] = {p.x, p.y, p.z, p.w};
                #pragma unroll
                for (int j = 0; j < 4; j++) {
                    sel[u * 8 + j * 2 + 0] += w * bf_lo(vs[j]);
                    sel[u * 8 + j * 2 + 1] += w * bf_hi(vs[j]);
                }
            }
        }
    }
    #pragma unroll
    for (int u = 0; u < 4; u++)
        *(float4*)&Ss[node_l][kc + u * 4] =
            make_float4(sel[u * 4], sel[u * 4 + 1], sel[u * 4 + 2], sel[u * 4 + 3]);
    __syncthreads();

    const int c0 = (tid & 7) * 5;
    float z[5];
    #pragma unroll
    for (int i = 0; i < 5; i++) z[i] = bs[c0 + i];
    for (int k = 0; k < HIDDEN; k += 4) {
        float4 s4 = *(const float4*)&Ss[node_l][k];
        #pragma unroll
        for (int i = 0; i < 5; i++) {
            float4 w4 = *(const float4*)&Wt[c0 + i][k];
            z[i] += s4.x * w4.x + s4.y * w4.y + s4.z * w4.z + s4.w * w4.w;
        }
    }
    float m = z[0];
    #pragma unroll
    for (int i = 1; i < 5; i++) m = fmaxf(m, z[i]);
    #pragma unroll
    for (int off = 1; off < 8; off <<= 1) m = fmaxf(m, __shfl_xor(m, off));
    float s = 0.f;
    #pragma unroll
    for (int i = 0; i < 5; i++) s += expf(z[i] - m);
    #pragma unroll
    for (int off = 1; off < 8; off <<= 1) s += __shfl_xor(s, off);
    float lg = m + logf(s);
    if (ng < N) {
        #pragma unroll
        for (int i = 0; i < 5; i++)
            out[(size_t)ng * NCLS + c0 + i] = z[i] - lg;
    }
}

// ---------------- launch ----------------

extern "C" void kernel_launch(void* const* d_in, const int* in_sizes, int n_in,
                              void* d_out, int out_size, void* d_ws, size_t ws_size,
                              hipStream_t stream) {
    const float* x      = (const float*)d_in[0];
    const int*   ei     = (const int*)d_in[1];
    const float* W_pre  = (const float*)d_in[2];
    const float* b_pre  = (const float*)d_in[3];
    const float* W_dep  = (const float*)d_in[4];
    const float* b_dep  = (const float*)d_in[5];
    const float* W_aggr = (const float*)d_in[6];
    const float* b_aggr = (const float*)d_in[7];
    const float* W_conv = (const float*)d_in[8];
    const float* b_conv = (const float*)d_in[9];
    const float* W_post = (const float*)d_in[10];
    const float* b_post = (const float*)d_in[11];

    const int N = in_sizes[0] / HIDDEN;
    const int E = in_sizes[1] / 2;
    const int nbuckets = (N + 255) >> 8;

    char* ws = (char*)d_ws;
    size_t off = 0;
    auto alloc = [&](size_t bytes) -> void* {
        void* p = ws + off;
        off += (bytes + 255) & ~(size_t)255;
        return p;
    };
    const size_t hstride = (size_t)N * HIDDEN;
    unsigned short* h_all  = (unsigned short*)alloc(5 * hstride * 2);  // h_0..h_4
    unsigned short* ht     = (unsigned short*)alloc(hstride * 2);
    unsigned char*  ht8    = (unsigned char*)alloc(hstride);           // fp8 gather copy
    float* cp       = (float*)alloc((size_t)N * 4);
    float* wsel     = (float*)alloc((size_t)4 * N * 4);
    float* ctrl     = (float*)alloc((size_t)N * 8 * 4);
    unsigned short* WpreT = (unsigned short*)alloc(128 * 128 * 2);
    unsigned short* WT    = (unsigned short*)alloc(4 * 144 * 128 * 2);
    int*   row_start= (int*)alloc((size_t)(N + 8) * 4);   // N+1 used (sentinel at [N])
    int*   bucket_cnt    = (int*)alloc(BMAX * 4);
    int*   bucket_base   = (int*)alloc(BMAX * 4);
    int*   bucket_cursor = (int*)alloc(BMAX * 4);
    int*   csr_off  = (int*)alloc((size_t)E * 4);
    unsigned* binned = (unsigned*)alloc((size_t)E * 4);

    hipMemsetAsync(bucket_cnt, 0, BMAX * 4, stream);

    int ebb = (E + 4095) / 4096;
    k_bcount<<<ebb, 256, 0, stream>>>(ei, E, bucket_cnt);
    k_bscan<<<1, 256, 0, stream>>>(bucket_cnt, nbuckets, bucket_base, bucket_cursor);
    k_bin<<<ebb, 256, 0, stream>>>(ei, E, bucket_cursor, binned);
    k_scatter<<<nbuckets, 256, 0, stream>>>(binned, bucket_base, bucket_cnt,
                                            row_start, csr_off, N);

    int wtot = 16384 + 4 * 18432;
    k_wprep<<<(wtot + 255) / 256, 256, 0, stream>>>(W_pre, W_conv, W_dep, W_aggr,
                                                    WpreT, WT);

    int gblk = (N + 127) / 128;
    k_gemm_mfma<true, false><<<gblk, 512, 0, stream>>>(x, WpreT, b_pre, h_all,
                                                       nullptr, nullptr, N, 1);

    int nb4 = (N + 3) / 4;
    for (int d = 0; d < 4; d++) {
        unsigned short* h_d  = h_all + (size_t)d * hstride;
        unsigned short* h_n  = h_all + (size_t)(d + 1) * hstride;
        k_gemm_mfma<false, true><<<gblk, 512, 0, stream>>>(h_d, WT + (size_t)d * 18432,
                                                           b_conv + (size_t)d * HIDDEN,
                                                           ht, ht8, ctrl, N, 0);
        k_depth<<<nb4, 256, 0, stream>>>(ht8, ht, h_n, cp, wsel + (size_t)d * N, ctrl,
                                         row_start, csr_off,
                                         b_dep, b_aggr, N, d == 0 ? 1 : 0);
    }
    k_post<<<(N + 31) / 32, 256, 0, stream>>>(h_all, hstride, wsel, N,
                                              W_post, b_post, (float*)d_out);
}